// Round 3
// baseline (595.597 us; speedup 1.0000x reference)
//
#include <hip/hip_runtime.h>

// ---- types / helpers -------------------------------------------------------
typedef __attribute__((ext_vector_type(8))) __bf16 bf16x8;   // 8 bf16 = 4 VGPRs
typedef __attribute__((ext_vector_type(4))) float  f32x4;
typedef unsigned short u16;

__device__ __forceinline__ u16 f2bf(float f) {
    union { float f; unsigned int i; } v; v.f = f;
    unsigned int r = v.i + 0x7fffu + ((v.i >> 16) & 1u);   // round-to-nearest-even
    return (u16)(r >> 16);
}
// pack two f32 -> two bf16 (round-half-up) in one v_perm
__device__ __forceinline__ unsigned pack2(float a, float b) {
    union { float f; unsigned u; } x, y; x.f = a; y.f = b;
    return __builtin_amdgcn_perm(y.u + 0x8000u, x.u + 0x8000u, 0x07060302u);
}
// load 8 consecutive f32 and convert to a bf16x8 MFMA fragment
__device__ __forceinline__ bf16x8 ldw_cvt(const float* __restrict__ p) {
    const float4 v0 = *(const float4*)p;
    const float4 v1 = *(const float4*)(p + 4);
    union { unsigned u[4]; bf16x8 v; } r;
    r.u[0] = pack2(v0.x, v0.y);
    r.u[1] = pack2(v0.z, v0.w);
    r.u[2] = pack2(v1.x, v1.y);
    r.u[3] = pack2(v1.z, v1.w);
    return r.v;
}

#define B_  64
#define S_  100
#define E_  512
#define H_  1024
#define VT_ 32000

// ---- K1: encmean[b][e] = (1/S)*sum_s concat(emb_in[src], emb_pos[pos]) ----
// f32 tables in, bf16 encmean out (A-operand of K2's MFMA).
__global__ void k1_encmean(const int* __restrict__ src, const int* __restrict__ pos,
                           const float* __restrict__ emb_in, const float* __restrict__ emb_pos,
                           u16* __restrict__ encmean) {
    int b = blockIdx.x;
    int t = threadIdx.x;                       // 256 threads
    __shared__ int sidx[S_], pidx[S_];
    if (t < S_) { sidx[t] = src[b * S_ + t]; pidx[t] = pos[b * S_ + t]; }
    __syncthreads();

    bool isPos = (t >= 128);
    int quad = isPos ? (t - 128) : t;          // 0..127 -> 4 f32 each
    const float* base = isPos ? emb_pos : emb_in;
    const int* idx  = isPos ? pidx : sidx;

    float a0 = 0.f, a1 = 0.f, a2 = 0.f, a3 = 0.f;
    for (int s = 0; s < S_; s++) {
        const float4 v = *(const float4*)(base + (size_t)idx[s] * E_ + quad * 4);
        a0 += v.x; a1 += v.y; a2 += v.z; a3 += v.w;
    }
    const float inv = 1.0f / (float)S_;
    int e = (isPos ? E_ : 0) + quad * 4;
    u16* o = encmean + (size_t)b * (2 * E_) + e;
    o[0] = f2bf(a0 * inv); o[1] = f2bf(a1 * inv); o[2] = f2bf(a2 * inv); o[3] = f2bf(a3 * inv);
}

// ---- MFMA GEMM helper: acc += A[64][K](bf16) * W[N][K](f32)^T -------------
// A-frag: lane holds A[m=lane&15][k=(lane>>4)*8+i];  B-frag mirrors with W row jt+n.
// C/D: col=lane&15 (n), row=(lane>>4)*4+reg (batch).
#define MFMA16(a, bfrag, c) __builtin_amdgcn_mfma_f32_16x16x32_bf16((a), (bfrag), (c), 0, 0, 0)

__device__ __forceinline__ void gemm_tile(const u16* __restrict__ A, int lda,
                                          const float* __restrict__ W, int ldw,
                                          int jt, int w, int m, int q, int Kel,
                                          f32x4 acc[4]) {
    const bf16x8* ar = (const bf16x8*)(A + (size_t)(w * 16 + m) * lda) + q;
    const float* w0 = W + (size_t)(jt +  0 + m) * ldw + q * 8;
    const float* w1 = W + (size_t)(jt + 16 + m) * ldw + q * 8;
    const float* w2 = W + (size_t)(jt + 32 + m) * ldw + q * 8;
    const float* w3 = W + (size_t)(jt + 48 + m) * ldw + q * 8;
    int nu = Kel >> 3;                          // #8-elem units along K
    #pragma unroll 2
    for (int kk = 0; kk < nu; kk += 4) {        // 32 K-elements per step
        bf16x8 a = ar[kk];
        acc[0] = MFMA16(a, ldw_cvt(w0 + kk * 8), acc[0]);
        acc[1] = MFMA16(a, ldw_cvt(w1 + kk * 8), acc[1]);
        acc[2] = MFMA16(a, ldw_cvt(w2 + kk * 8), acc[2]);
        acc[3] = MFMA16(a, ldw_cvt(w3 + kk * 8), acc[3]);
    }
}

// ---- K2: h0 = encmean @ W_scale^T + b_scale  (f32 + bf16 copies) ----------
__global__ void k2_h0(const u16* __restrict__ encmean, const float* __restrict__ Wscale,
                      const float* __restrict__ bscale,
                      float* __restrict__ h0f, u16* __restrict__ h0b) {
    int t = threadIdx.x, lane = t & 63, w = t >> 6, m = lane & 15, q = lane >> 4;
    int jt = blockIdx.x * 64;
    f32x4 acc[4] = {{0,0,0,0},{0,0,0,0},{0,0,0,0},{0,0,0,0}};
    gemm_tile(encmean, 2 * E_, Wscale, 2 * E_, jt, w, m, q, 2 * E_, acc);
    #pragma unroll
    for (int f = 0; f < 4; f++) {
        int j = jt + 16 * f + m;
        float bias = bscale[j];
        #pragma unroll
        for (int r = 0; r < 4; r++) {
            int b = w * 16 + q * 4 + r;
            float v = acc[f][r] + bias;
            h0f[(size_t)b * H_ + j] = v;
            h0b[(size_t)b * H_ + j] = f2bf(v);
        }
    }
}

// ---- K3: energy -> softmax -> context; x = [emb_out[tgt], context] (bf16) -
__global__ void k3_attn(const int* __restrict__ src, const int* __restrict__ pos,
                        const int* __restrict__ tgt,
                        const float* __restrict__ emb_in, const float* __restrict__ emb_pos,
                        const float* __restrict__ emb_out,
                        const float* __restrict__ h0f, u16* __restrict__ x) {
    int b = blockIdx.x, t = threadIdx.x;       // 256 threads
    __shared__ float h0s[2 * E_];
    __shared__ int sidx[S_], pidx[S_];
    __shared__ float energy[S_];
    __shared__ float align_s[S_];

    for (int i = t; i < 2 * E_; i += 256) h0s[i] = h0f[(size_t)b * H_ + i];
    if (t < S_) { sidx[t] = src[b * S_ + t]; pidx[t] = pos[b * S_ + t]; }
    __syncthreads();

    int lane = t & 63, w = t >> 6;
    for (int s = w; s < S_; s += 4) {
        const float* ri = emb_in  + (size_t)sidx[s] * E_;
        const float* rp = emb_pos + (size_t)pidx[s] * E_;
        float acc = 0.f;
        #pragma unroll
        for (int ii = 0; ii < 8; ii++) { int k = lane + 64 * ii; acc += ri[k] * h0s[k]; }
        #pragma unroll
        for (int ii = 0; ii < 8; ii++) { int k = lane + 64 * ii; acc += rp[k] * h0s[E_ + k]; }
        #pragma unroll
        for (int off = 32; off; off >>= 1) acc += __shfl_down(acc, off);
        if (lane == 0) energy[s] = acc;
    }
    __syncthreads();

    if (t < 64) {
        float e0 = energy[t];
        float e1 = (t + 64 < S_) ? energy[t + 64] : -1e30f;
        float mx = fmaxf(e0, e1);
        #pragma unroll
        for (int off = 32; off; off >>= 1) mx = fmaxf(mx, __shfl_xor(mx, off));
        float p0 = expf(e0 - mx);
        float p1 = (t + 64 < S_) ? expf(e1 - mx) : 0.f;
        float ss = p0 + p1;
        #pragma unroll
        for (int off = 32; off; off >>= 1) ss += __shfl_xor(ss, off);
        float inv = 1.0f / (ss * (float)S_);   // fold torch.mean's 1/S here
        align_s[t] = p0 * inv;
        if (t + 64 < S_) align_s[t + 64] = p1 * inv;
    }
    __syncthreads();

    if (t < 128) {
        // context: octet o covers 8 f32 of the 1024-wide context
        int o = t;
        bool isPos = (o >= 64);
        const float* base = isPos ? emb_pos : emb_in;
        const int* idx  = isPos ? pidx : sidx;
        int eo = (o & 63) * 8;
        float c[8] = {0,0,0,0,0,0,0,0};
        for (int s = 0; s < S_; s++) {
            const float* row = base + (size_t)idx[s] * E_ + eo;
            float al = align_s[s];
            const float4 v0 = *(const float4*)(row);
            const float4 v1 = *(const float4*)(row + 4);
            c[0] += al * v0.x; c[1] += al * v0.y; c[2] += al * v0.z; c[3] += al * v0.w;
            c[4] += al * v1.x; c[5] += al * v1.y; c[6] += al * v1.z; c[7] += al * v1.w;
        }
        u16* xo = x + (size_t)b * (E_ + H_) + E_ + o * 8;
        #pragma unroll
        for (int i = 0; i < 8; i++) xo[i] = f2bf(c[i]);
    } else {
        int i = t - 128;                        // 128 threads x 4 elems = 512
        int tw = tgt[b];
        const float4 v = *((const float4*)(emb_out + (size_t)tw * E_) + i);
        ushort4 o; o.x = f2bf(v.x); o.y = f2bf(v.y); o.z = f2bf(v.z); o.w = f2bf(v.w);
        *((ushort4*)(x + (size_t)b * (E_ + H_)) + i) = o;
    }
}

// ---- K4: h = tanh(x@W_ih^T + b_ih + h0@W_hh^T + b_hh) ---------------------
// writes f32 h into d_out (Output 1) and bf16 h into ws (A of K5)
__global__ void k4_h(const u16* __restrict__ xb, const float* __restrict__ Wih,
                     const float* __restrict__ bih,
                     const u16* __restrict__ h0b, const float* __restrict__ Whh,
                     const float* __restrict__ bhh,
                     float* __restrict__ houtf, u16* __restrict__ hbf) {
    int t = threadIdx.x, lane = t & 63, w = t >> 6, m = lane & 15, q = lane >> 4;
    int jt = blockIdx.x * 64;
    f32x4 acc[4] = {{0,0,0,0},{0,0,0,0},{0,0,0,0},{0,0,0,0}};
    gemm_tile(xb,  E_ + H_, Wih, E_ + H_, jt, w, m, q, E_ + H_, acc);
    gemm_tile(h0b, H_,      Whh, H_,      jt, w, m, q, H_,      acc);
    #pragma unroll
    for (int f = 0; f < 4; f++) {
        int j = jt + 16 * f + m;
        float bias = bih[j] + bhh[j];
        #pragma unroll
        for (int r = 0; r < 4; r++) {
            int b = w * 16 + q * 4 + r;
            float v = tanhf(acc[f][r] + bias);
            houtf[(size_t)b * H_ + j] = v;
            hbf[(size_t)b * H_ + j] = f2bf(v);
        }
    }
}

// ---- K5: out = h @ W_proj^T + b_proj  (131 MB f32 weights, HBM-bound) -----
__global__ void k5_out(const u16* __restrict__ hb, const float* __restrict__ Wp,
                       const float* __restrict__ bp, float* __restrict__ out) {
    int t = threadIdx.x, lane = t & 63, w = t >> 6, m = lane & 15, q = lane >> 4;
    int jt = blockIdx.x * 64;
    f32x4 acc[4] = {{0,0,0,0},{0,0,0,0},{0,0,0,0},{0,0,0,0}};
    gemm_tile(hb, H_, Wp, H_, jt, w, m, q, H_, acc);
    #pragma unroll
    for (int f = 0; f < 4; f++) {
        int j = jt + 16 * f + m;
        float bias = bp[j];
        #pragma unroll
        for (int r = 0; r < 4; r++) {
            int b = w * 16 + q * 4 + r;
            out[(size_t)b * VT_ + j] = acc[f][r] + bias;
        }
    }
}

// ---- launch ---------------------------------------------------------------
extern "C" void kernel_launch(void* const* d_in, const int* in_sizes, int n_in,
                              void* d_out, int out_size, void* d_ws, size_t ws_size,
                              hipStream_t stream) {
    const int*   src     = (const int*)d_in[0];
    const int*   pos     = (const int*)d_in[1];
    const int*   tgt     = (const int*)d_in[2];
    // d_in[3] source_lengths, d_in[4] max_len: unused by the math
    const float* emb_in  = (const float*)d_in[5];
    const float* emb_out = (const float*)d_in[6];
    const float* emb_pos = (const float*)d_in[7];
    const float* Wscale  = (const float*)d_in[8];
    const float* bscale  = (const float*)d_in[9];
    const float* Wih     = (const float*)d_in[10];
    const float* bih     = (const float*)d_in[11];
    const float* Whh     = (const float*)d_in[12];
    const float* bhh     = (const float*)d_in[13];
    const float* Wproj   = (const float*)d_in[14];
    const float* bproj   = (const float*)d_in[15];

    char* ws = (char*)d_ws;
    u16*   encmean = (u16*)(ws);                 // 64*1024*2   = 131072 B
    float* h0f     = (float*)(ws + 131072);      // 64*1024*4   = 262144 B
    u16*   h0b     = (u16*)(ws + 393216);        // 64*1024*2   = 131072 B
    u16*   xb      = (u16*)(ws + 524288);        // 64*1536*2   = 196608 B
    u16*   hbf     = (u16*)(ws + 720896);        // 64*1024*2   = 131072 B

    float* out   = (float*)d_out;                // [64][32000] f32
    float* houtf = out + (size_t)B_ * VT_;       // [64][1024]  f32 (Output 1)

    hipLaunchKernelGGL(k1_encmean, dim3(B_),        dim3(256), 0, stream,
                       src, pos, emb_in, emb_pos, encmean);
    hipLaunchKernelGGL(k2_h0,      dim3(H_ / 64),   dim3(256), 0, stream,
                       encmean, Wscale, bscale, h0f, h0b);
    hipLaunchKernelGGL(k3_attn,    dim3(B_),        dim3(256), 0, stream,
                       src, pos, tgt, emb_in, emb_pos, emb_out, h0f, xb);
    hipLaunchKernelGGL(k4_h,       dim3(H_ / 64),   dim3(256), 0, stream,
                       xb, Wih, bih, h0b, Whh, bhh, houtf, hbf);
    hipLaunchKernelGGL(k5_out,     dim3(VT_ / 64),  dim3(256), 0, stream,
                       hbf, Wproj, bproj, out);
}

// Round 4
// 372.878 us; speedup vs baseline: 1.5973x; 1.5973x over previous
//
#include <hip/hip_runtime.h>

// ---- types / helpers -------------------------------------------------------
typedef __attribute__((ext_vector_type(8))) __bf16 bf16x8;   // 8 bf16 = 4 VGPRs
typedef __attribute__((ext_vector_type(4))) float  f32x4;
typedef unsigned short u16;

__device__ __forceinline__ u16 f2bf(float f) {
    union { float f; unsigned int i; } v; v.f = f;
    unsigned int r = v.i + 0x7fffu + ((v.i >> 16) & 1u);   // round-to-nearest-even
    return (u16)(r >> 16);
}
// pack two f32 -> two bf16 (lo=a, hi=b) in one v_perm
__device__ __forceinline__ unsigned pack2(float a, float b) {
    union { float f; unsigned u; } x, y; x.f = a; y.f = b;
    return __builtin_amdgcn_perm(y.u + 0x8000u, x.u + 0x8000u, 0x07060302u);
}

#define B_  64
#define S_  100
#define E_  512
#define H_  1024
#define VT_ 32000
#define Kc  128          // K-chunk in f32 elements
#define PITCH 128        // LDS row pitch in u16 (XOR-swizzled, no pad needed)

// ---- K1: encmean[b][e] = (1/S)*sum_s concat(emb_in[src], emb_pos[pos]) ----
// grid (B, 4): blockIdx.y = quarter of the 1024-wide output (256 f32 each).
// 256 thr = 64 float4-columns x 4 s-groups (25 s each) -> LDS reduce.
__global__ __launch_bounds__(256, 1)
void k1_encmean(const int* __restrict__ src, const int* __restrict__ pos,
                const float* __restrict__ emb_in, const float* __restrict__ emb_pos,
                u16* __restrict__ encmean) {
    int b = blockIdx.x, q4 = blockIdx.y, t = threadIdx.x;
    __shared__ int sidx[S_], pidx[S_];
    __shared__ float part[256][4];
    if (t < S_) { sidx[t] = src[b * S_ + t]; pidx[t] = pos[b * S_ + t]; }
    __syncthreads();

    int f4 = t & 63, g = t >> 6;
    bool isPos = (q4 >= 2);
    const float* base = isPos ? emb_pos : emb_in;
    const int*   idx  = isPos ? pidx : sidx;
    int col = (q4 & 1) * 256 + f4 * 4;          // column within the 512-wide table

    float a0 = 0.f, a1 = 0.f, a2 = 0.f, a3 = 0.f;
    int s0 = g * 25;
    #pragma unroll 5
    for (int s = s0; s < s0 + 25; s++) {
        const float4 v = *(const float4*)(base + (size_t)idx[s] * E_ + col);
        a0 += v.x; a1 += v.y; a2 += v.z; a3 += v.w;
    }
    part[t][0] = a0; part[t][1] = a1; part[t][2] = a2; part[t][3] = a3;
    __syncthreads();

    if (t < 64) {
        const float inv = 1.0f / (float)S_;
        float r0 = 0.f, r1 = 0.f, r2 = 0.f, r3 = 0.f;
        #pragma unroll
        for (int g2 = 0; g2 < 4; g2++) {
            r0 += part[g2 * 64 + t][0]; r1 += part[g2 * 64 + t][1];
            r2 += part[g2 * 64 + t][2]; r3 += part[g2 * 64 + t][3];
        }
        int e = q4 * 256 + t * 4;
        u16* o = encmean + (size_t)b * (2 * E_) + e;
        o[0] = f2bf(r0 * inv); o[1] = f2bf(r1 * inv);
        o[2] = f2bf(r2 * inv); o[3] = f2bf(r3 * inv);
    }
}

// ---- LDS-staged double-buffered MFMA GEMM: acc += A[64][KTOT] * W[64j][KTOT]^T
// A: bf16 in ws (L2-hot, read direct). W: f32, staged coalesced -> bf16 LDS.
// LDS layout: row rr (0..63), 16B-unit U (0..15) stored at U ^ (rr & 15).
// A-frag: lane(m=lane&15, q=lane>>4) holds A[w*16+m][k0 + q*8 ..+8]
// B-frag: row jt+f*16+m, same k slice.  C/D: col=lane&15, row=(lane>>4)*4+reg.
#define MFMA16(a, bfrag, c) __builtin_amdgcn_mfma_f32_16x16x32_bf16((a), (bfrag), (c), 0, 0, 0)

template<int KTOT>
__device__ __forceinline__ void gemm_lds(const u16* __restrict__ A,
                                         const float* __restrict__ W,
                                         int jt, u16* __restrict__ ldsW,
                                         f32x4 acc[4], int t) {
    constexpr int NC = KTOT / Kc;
    const int lane = t & 63, w = t >> 6, m = lane & 15, q = lane >> 4;
    const int r = t >> 2, c4 = t & 3;          // staging: 4 threads per W row
    const float* wsrc = W + (size_t)(jt + r) * KTOT + c4 * 4;
    const u16*   arow = A + (size_t)(w * 16 + m) * KTOT + q * 8;
    const int halfoff = (c4 & 1) * 4;          // u16 offset within 16B unit

    float4 v[8];
    // ---- prologue: stage chunk 0 into buf 0 ----
    #pragma unroll
    for (int i = 0; i < 8; i++) v[i] = *(const float4*)(wsrc + i * 16);
    #pragma unroll
    for (int i = 0; i < 8; i++) {
        int U = (c4 >> 1) + 2 * i;
        uint2 p; p.x = pack2(v[i].x, v[i].y); p.y = pack2(v[i].z, v[i].w);
        *(uint2*)(ldsW + r * PITCH + ((U ^ (r & 15)) * 8) + halfoff) = p;
    }
    __syncthreads();

    for (int c = 0; c < NC; c++) {
        // issue next chunk's global loads (land while we MFMA)
        if (c + 1 < NC) {
            #pragma unroll
            for (int i = 0; i < 8; i++)
                v[i] = *(const float4*)(wsrc + (c + 1) * Kc + i * 16);
        }
        // compute on buf c&1
        const u16* lb = ldsW + (c & 1) * (64 * PITCH);
        const u16* ar = arow + c * Kc;
        #pragma unroll
        for (int ks = 0; ks < 4; ks++) {
            bf16x8 a = *(const bf16x8*)(ar + ks * 32);
            #pragma unroll
            for (int f = 0; f < 4; f++) {
                int rr = f * 16 + m;
                int U  = ks * 4 + q;
                bf16x8 bfr = *(const bf16x8*)(lb + rr * PITCH + ((U ^ (rr & 15)) * 8));
                acc[f] = MFMA16(a, bfr, acc[f]);
            }
        }
        // write the staged chunk
        if (c + 1 < NC) {
            u16* wd = ldsW + ((c + 1) & 1) * (64 * PITCH) + r * PITCH;
            #pragma unroll
            for (int i = 0; i < 8; i++) {
                int U = (c4 >> 1) + 2 * i;
                uint2 p; p.x = pack2(v[i].x, v[i].y); p.y = pack2(v[i].z, v[i].w);
                *(uint2*)(wd + ((U ^ (r & 15)) * 8) + halfoff) = p;
            }
        }
        __syncthreads();
    }
}

// ---- K2: h0 = encmean @ W_scale^T + b_scale  (f32 + bf16 copies) ----------
__global__ __launch_bounds__(256, 1)
void k2_h0(const u16* __restrict__ encmean, const float* __restrict__ Wscale,
           const float* __restrict__ bscale,
           float* __restrict__ h0f, u16* __restrict__ h0b) {
    __shared__ u16 ldsW[2 * 64 * PITCH];
    int t = threadIdx.x, lane = t & 63, w = t >> 6, m = lane & 15, q = lane >> 4;
    int jt = blockIdx.x * 64;
    f32x4 acc[4] = {{0,0,0,0},{0,0,0,0},{0,0,0,0},{0,0,0,0}};
    gemm_lds<2 * E_>(encmean, Wscale, jt, ldsW, acc, t);
    #pragma unroll
    for (int f = 0; f < 4; f++) {
        int j = jt + 16 * f + m;
        float bias = bscale[j];
        #pragma unroll
        for (int r = 0; r < 4; r++) {
            int b = w * 16 + q * 4 + r;
            float vv = acc[f][r] + bias;
            h0f[(size_t)b * H_ + j] = vv;
            h0b[(size_t)b * H_ + j] = f2bf(vv);
        }
    }
}

// ---- K3: energy -> softmax -> context; x = [emb_out[tgt], context] (bf16) -
__global__ __launch_bounds__(256, 1)
void k3_attn(const int* __restrict__ src, const int* __restrict__ pos,
             const int* __restrict__ tgt,
             const float* __restrict__ emb_in, const float* __restrict__ emb_pos,
             const float* __restrict__ emb_out,
             const float* __restrict__ h0f, u16* __restrict__ x) {
    int b = blockIdx.x, t = threadIdx.x;       // 256 threads
    __shared__ float h0s[2 * E_];
    __shared__ int sidx[S_], pidx[S_];
    __shared__ float energy[S_];
    __shared__ float align_s[S_];

    for (int i = t; i < 2 * E_; i += 256) h0s[i] = h0f[(size_t)b * H_ + i];
    if (t < S_) { sidx[t] = src[b * S_ + t]; pidx[t] = pos[b * S_ + t]; }
    __syncthreads();

    int lane = t & 63, w = t >> 6;
    for (int s = w; s < S_; s += 4) {
        const float* ri = emb_in  + (size_t)sidx[s] * E_;
        const float* rp = emb_pos + (size_t)pidx[s] * E_;
        float acc = 0.f;
        #pragma unroll
        for (int ii = 0; ii < 8; ii++) { int k = lane + 64 * ii; acc += ri[k] * h0s[k]; }
        #pragma unroll
        for (int ii = 0; ii < 8; ii++) { int k = lane + 64 * ii; acc += rp[k] * h0s[E_ + k]; }
        #pragma unroll
        for (int off = 32; off; off >>= 1) acc += __shfl_down(acc, off);
        if (lane == 0) energy[s] = acc;
    }
    __syncthreads();

    if (t < 64) {
        float e0 = energy[t];
        float e1 = (t + 64 < S_) ? energy[t + 64] : -1e30f;
        float mx = fmaxf(e0, e1);
        #pragma unroll
        for (int off = 32; off; off >>= 1) mx = fmaxf(mx, __shfl_xor(mx, off));
        float p0 = expf(e0 - mx);
        float p1 = (t + 64 < S_) ? expf(e1 - mx) : 0.f;
        float ss = p0 + p1;
        #pragma unroll
        for (int off = 32; off; off >>= 1) ss += __shfl_xor(ss, off);
        float inv = 1.0f / (ss * (float)S_);   // fold torch.mean's 1/S here
        align_s[t] = p0 * inv;
        if (t + 64 < S_) align_s[t + 64] = p1 * inv;
    }
    __syncthreads();

    if (t < 128) {
        int o = t;
        bool isPos = (o >= 64);
        const float* base = isPos ? emb_pos : emb_in;
        const int* idx  = isPos ? pidx : sidx;
        int eo = (o & 63) * 8;
        float c[8] = {0,0,0,0,0,0,0,0};
        for (int s = 0; s < S_; s++) {
            const float* row = base + (size_t)idx[s] * E_ + eo;
            float al = align_s[s];
            const float4 v0 = *(const float4*)(row);
            const float4 v1 = *(const float4*)(row + 4);
            c[0] += al * v0.x; c[1] += al * v0.y; c[2] += al * v0.z; c[3] += al * v0.w;
            c[4] += al * v1.x; c[5] += al * v1.y; c[6] += al * v1.z; c[7] += al * v1.w;
        }
        u16* xo = x + (size_t)b * (E_ + H_) + E_ + o * 8;
        #pragma unroll
        for (int i = 0; i < 8; i++) xo[i] = f2bf(c[i]);
    } else {
        int i = t - 128;                        // 128 threads x 4 elems = 512
        int tw = tgt[b];
        const float4 v = *((const float4*)(emb_out + (size_t)tw * E_) + i);
        ushort4 o; o.x = f2bf(v.x); o.y = f2bf(v.y); o.z = f2bf(v.z); o.w = f2bf(v.w);
        *((ushort4*)(x + (size_t)b * (E_ + H_)) + i) = o;
    }
}

// ---- K4: h = tanh(x@W_ih^T + b_ih + h0@W_hh^T + b_hh) ---------------------
__global__ __launch_bounds__(256, 1)
void k4_h(const u16* __restrict__ xb, const float* __restrict__ Wih,
          const float* __restrict__ bih,
          const u16* __restrict__ h0b, const float* __restrict__ Whh,
          const float* __restrict__ bhh,
          float* __restrict__ houtf, u16* __restrict__ hbf) {
    __shared__ u16 ldsW[2 * 64 * PITCH];
    int t = threadIdx.x, lane = t & 63, w = t >> 6, m = lane & 15, q = lane >> 4;
    int jt = blockIdx.x * 64;
    f32x4 acc[4] = {{0,0,0,0},{0,0,0,0},{0,0,0,0},{0,0,0,0}};
    gemm_lds<E_ + H_>(xb,  Wih, jt, ldsW, acc, t);
    gemm_lds<H_>     (h0b, Whh, jt, ldsW, acc, t);
    #pragma unroll
    for (int f = 0; f < 4; f++) {
        int j = jt + 16 * f + m;
        float bias = bih[j] + bhh[j];
        #pragma unroll
        for (int r = 0; r < 4; r++) {
            int b = w * 16 + q * 4 + r;
            float vv = tanhf(acc[f][r] + bias);
            houtf[(size_t)b * H_ + j] = vv;
            hbf[(size_t)b * H_ + j] = f2bf(vv);
        }
    }
}

// ---- K5: out = h @ W_proj^T + b_proj  (131 MB f32 weights, HBM-bound) -----
__global__ __launch_bounds__(256, 1)
void k5_out(const u16* __restrict__ hb, const float* __restrict__ Wp,
            const float* __restrict__ bp, float* __restrict__ out) {
    __shared__ u16 ldsW[2 * 64 * PITCH];
    int t = threadIdx.x, lane = t & 63, w = t >> 6, m = lane & 15, q = lane >> 4;
    int jt = blockIdx.x * 64;
    f32x4 acc[4] = {{0,0,0,0},{0,0,0,0},{0,0,0,0},{0,0,0,0}};
    gemm_lds<H_>(hb, Wp, jt, ldsW, acc, t);
    #pragma unroll
    for (int f = 0; f < 4; f++) {
        int j = jt + 16 * f + m;
        float bias = bp[j];
        #pragma unroll
        for (int r = 0; r < 4; r++) {
            int b = w * 16 + q * 4 + r;
            out[(size_t)b * VT_ + j] = acc[f][r] + bias;
        }
    }
}

// ---- launch ---------------------------------------------------------------
extern "C" void kernel_launch(void* const* d_in, const int* in_sizes, int n_in,
                              void* d_out, int out_size, void* d_ws, size_t ws_size,
                              hipStream_t stream) {
    const int*   src     = (const int*)d_in[0];
    const int*   pos     = (const int*)d_in[1];
    const int*   tgt     = (const int*)d_in[2];
    const float* emb_in  = (const float*)d_in[5];
    const float* emb_out = (const float*)d_in[6];
    const float* emb_pos = (const float*)d_in[7];
    const float* Wscale  = (const float*)d_in[8];
    const float* bscale  = (const float*)d_in[9];
    const float* Wih     = (const float*)d_in[10];
    const float* bih     = (const float*)d_in[11];
    const float* Whh     = (const float*)d_in[12];
    const float* bhh     = (const float*)d_in[13];
    const float* Wproj   = (const float*)d_in[14];
    const float* bproj   = (const float*)d_in[15];

    char* ws = (char*)d_ws;
    u16*   encmean = (u16*)(ws);                 // 64*1024*2   = 131072 B
    float* h0f     = (float*)(ws + 131072);      // 64*1024*4   = 262144 B
    u16*   h0b     = (u16*)(ws + 393216);        // 64*1024*2   = 131072 B
    u16*   xb      = (u16*)(ws + 524288);        // 64*1536*2   = 196608 B
    u16*   hbf     = (u16*)(ws + 720896);        // 64*1024*2   = 131072 B

    float* out   = (float*)d_out;                // [64][32000] f32
    float* houtf = out + (size_t)B_ * VT_;       // [64][1024]  f32 (Output 1)

    hipLaunchKernelGGL(k1_encmean, dim3(B_, 4),     dim3(256), 0, stream,
                       src, pos, emb_in, emb_pos, encmean);
    hipLaunchKernelGGL(k2_h0,      dim3(H_ / 64),   dim3(256), 0, stream,
                       encmean, Wscale, bscale, h0f, h0b);
    hipLaunchKernelGGL(k3_attn,    dim3(B_),        dim3(256), 0, stream,
                       src, pos, tgt, emb_in, emb_pos, emb_out, h0f, xb);
    hipLaunchKernelGGL(k4_h,       dim3(H_ / 64),   dim3(256), 0, stream,
                       xb, Wih, bih, h0b, Whh, bhh, houtf, hbf);
    hipLaunchKernelGGL(k5_out,     dim3(VT_ / 64),  dim3(256), 0, stream,
                       hbf, Wproj, bproj, out);
}